// Round 6
// baseline (15300.204 us; speedup 1.0000x reference)
//
#include <hip/hip_runtime.h>
#include <math.h>

#define NSTEP 4095   // T-1 sequence steps
#define EDIM  512
#define HDIM  1024
#define GDIM  4096   // 4*H
#define KDIM  1024   // 2E == H == 1024 for both GEMMs
#define CDIM  1221
#define SNWG  64     // scan workgroups (16 units each) -- proven poll fanout
#define SNT   1024   // scan threads per WG (16 waves -> 4/SIMD latency hiding)
#define HSPAD 20     // 16 cols + 4 pad per segment (writes CF, reads <=2-way)

// Pin a float4's lanes into VGPRs via an empty asm INSIDE the step loop:
// the value becomes loop-carried through the asm, so the compiler cannot
// rematerialize the weight loads from memory each iteration (v5->v6 proved
// this: in-loop pin cut the step 3.38 -> 2.24 us).
#define PIN4(v) asm volatile("" : "+v"((v).x), "+v"((v).y), "+v"((v).z), "+v"((v).w))

__device__ __forceinline__ float sigmoidf_(float v) {
    return 1.0f / (1.0f + __expf(-v));
}
__device__ __forceinline__ float tanhf_(float v) {
    v = fminf(fmaxf(v, -15.0f), 15.0f);      // avoid inf/inf NaN
    const float e2 = __expf(2.0f * v);
    return (e2 - 1.0f) / (e2 + 1.0f);
}

// ---------------------------------------------------------------------------
// GEMM1: xg[m][n] = sum_k A[m][k]*W_ih[n][k] + b_ih[n] + b_hh[n]
//   A[m][k] = emb[x[m]][k] (k<512) ; emb[x[4095]][k-512] (k>=512)
// ---------------------------------------------------------------------------
__global__ __launch_bounds__(256) void gemm_emb_kernel(
    const int* __restrict__ x, const float* __restrict__ emb,
    const float* __restrict__ W, const float* __restrict__ b_ih,
    const float* __restrict__ b_hh, float* __restrict__ xg)
{
    __shared__ float As[8][128];
    __shared__ float Bs[8][128];
    const int tid = threadIdx.x;
    const int bm = blockIdx.y * 128, bn = blockIdx.x * 128;
    const int tx = tid & 15, ty = tid >> 4;
    const int lrow = tid >> 1;
    const int lk4  = (tid & 1) * 4;
    const int lastTok = x[NSTEP];
    const int am = bm + lrow;
    const int tokRow = (am < NSTEP) ? x[am] : 0;
    const int bnrow = bn + lrow;

    float acc[8][8];
#pragma unroll
    for (int i = 0; i < 8; ++i)
#pragma unroll
        for (int j = 0; j < 8; ++j) acc[i][j] = 0.0f;

    for (int k0 = 0; k0 < KDIM; k0 += 8) {
        const int k = k0 + lk4;
        float4 av = make_float4(0.f, 0.f, 0.f, 0.f);
        if (am < NSTEP) {
            const int tok = (k < EDIM) ? tokRow : lastTok;
            const int kk  = (k < EDIM) ? k : (k - EDIM);
            av = *(const float4*)(emb + (size_t)tok * EDIM + kk);
        }
        const float4 bv = *(const float4*)(W + (size_t)bnrow * KDIM + k);
        __syncthreads();
        As[lk4 + 0][lrow] = av.x; As[lk4 + 1][lrow] = av.y;
        As[lk4 + 2][lrow] = av.z; As[lk4 + 3][lrow] = av.w;
        Bs[lk4 + 0][lrow] = bv.x; Bs[lk4 + 1][lrow] = bv.y;
        Bs[lk4 + 2][lrow] = bv.z; Bs[lk4 + 3][lrow] = bv.w;
        __syncthreads();
#pragma unroll
        for (int kk = 0; kk < 8; ++kk) {
            const float4 a0 = *(const float4*)&As[kk][ty * 4];
            const float4 a1 = *(const float4*)&As[kk][ty * 4 + 64];
            const float4 b0 = *(const float4*)&Bs[kk][tx * 4];
            const float4 b1 = *(const float4*)&Bs[kk][tx * 4 + 64];
            const float a[8] = {a0.x, a0.y, a0.z, a0.w, a1.x, a1.y, a1.z, a1.w};
            const float b[8] = {b0.x, b0.y, b0.z, b0.w, b1.x, b1.y, b1.z, b1.w};
#pragma unroll
            for (int i = 0; i < 8; ++i)
#pragma unroll
                for (int j = 0; j < 8; ++j) acc[i][j] += a[i] * b[j];
        }
    }
#pragma unroll
    for (int i = 0; i < 8; ++i) {
        const int m = bm + ((i < 4) ? (ty * 4 + i) : (64 + ty * 4 + i - 4));
        if (m >= NSTEP) continue;
#pragma unroll
        for (int j = 0; j < 8; ++j) {
            const int n = bn + ((j < 4) ? (tx * 4 + j) : (64 + tx * 4 + j - 4));
            xg[(size_t)m * GDIM + n] = acc[i][j] + b_ih[n] + b_hh[n];
        }
    }
}

// ---------------------------------------------------------------------------
// GEMM2: out[m][n] = sum_k hs[m][k]*W_out[n][k] + b_out[n]   (N=1221)
// ---------------------------------------------------------------------------
__global__ __launch_bounds__(256) void gemm_out_kernel(
    const float* __restrict__ A, const float* __restrict__ W,
    const float* __restrict__ bias, float* __restrict__ C)
{
    __shared__ float As[8][128];
    __shared__ float Bs[8][128];
    const int tid = threadIdx.x;
    const int bm = blockIdx.y * 128, bn = blockIdx.x * 128;
    const int tx = tid & 15, ty = tid >> 4;
    const int lrow = tid >> 1;
    const int lk4  = (tid & 1) * 4;
    const int am = bm + lrow;
    const int bnrow = bn + lrow;

    float acc[8][8];
#pragma unroll
    for (int i = 0; i < 8; ++i)
#pragma unroll
        for (int j = 0; j < 8; ++j) acc[i][j] = 0.0f;

    for (int k0 = 0; k0 < KDIM; k0 += 8) {
        const int k = k0 + lk4;
        float4 av = make_float4(0.f, 0.f, 0.f, 0.f);
        if (am < NSTEP) av = *(const float4*)(A + (size_t)am * KDIM + k);
        float4 bv = make_float4(0.f, 0.f, 0.f, 0.f);
        if (bnrow < CDIM) bv = *(const float4*)(W + (size_t)bnrow * KDIM + k);
        __syncthreads();
        As[lk4 + 0][lrow] = av.x; As[lk4 + 1][lrow] = av.y;
        As[lk4 + 2][lrow] = av.z; As[lk4 + 3][lrow] = av.w;
        Bs[lk4 + 0][lrow] = bv.x; Bs[lk4 + 1][lrow] = bv.y;
        Bs[lk4 + 2][lrow] = bv.z; Bs[lk4 + 3][lrow] = bv.w;
        __syncthreads();
#pragma unroll
        for (int kk = 0; kk < 8; ++kk) {
            const float4 a0 = *(const float4*)&As[kk][ty * 4];
            const float4 a1 = *(const float4*)&As[kk][ty * 4 + 64];
            const float4 b0 = *(const float4*)&Bs[kk][tx * 4];
            const float4 b1 = *(const float4*)&Bs[kk][tx * 4 + 64];
            const float a[8] = {a0.x, a0.y, a0.z, a0.w, a1.x, a1.y, a1.z, a1.w};
            const float b[8] = {b0.x, b0.y, b0.z, b0.w, b1.x, b1.y, b1.z, b1.w};
#pragma unroll
            for (int i = 0; i < 8; ++i)
#pragma unroll
                for (int j = 0; j < 8; ++j) acc[i][j] += a[i] * b[j];
        }
    }
#pragma unroll
    for (int i = 0; i < 8; ++i) {
        const int m = bm + ((i < 4) ? (ty * 4 + i) : (64 + ty * 4 + i - 4));
        if (m >= NSTEP) continue;
#pragma unroll
        for (int j = 0; j < 8; ++j) {
            const int n = bn + ((j < 4) ? (tx * 4 + j) : (64 + tx * 4 + j - 4));
            if (n < CDIM) C[(size_t)m * CDIM + n] = acc[i][j] + bias[n];
        }
    }
}

// ---------------------------------------------------------------------------
// Persistent LSTM scan, v7 (resubmission -- Round-5 bench died with a
// container-level infra error before producing any kernel data; structural
// audit found no hang risk: 64 co-resident WGs, v3-proven register budget,
// publish-before-spin program order, coherence-safe stale tags).
// v7 = v6's row-reuse + wave-local tail, restored to v3's 16-wave TLP.
// 64 WGs x 1024 threads (16 waves). WAVE w owns unit blockIdx.x*16+w
// entirely: lane l holds 4 gate rows x 16 cols (cols l*16..l*16+15) = 64
// weight floats (v3's proven footprint), pinned loop-carried.
//   - Per-WG LDS read stays at v6's 64KB/step (each wave reads h once).
//   - Tail fully wave-local: 6-stage butterfly (xg folded into lanes 0..3
//     before it), nonlinearity redundant in all 64 lanes, lane 0 publishes.
//     One barrier per step.
//   - h_s seg-major PAD=20: h[k] at (k>>4)*20+(k&15). Writes conflict-free;
//     b128 reads worst-case 2-way (lane L vs L+8) = free (m136).
//   - Handoff unchanged: tagged payloads hb[par][k]=(step<<32)|bits(h),
//     parity double-buffer, one u64 poll per thread per round.
// ---------------------------------------------------------------------------
__global__ __launch_bounds__(1024, 4) void scan_kernel(
    const float* __restrict__ xg, const float* __restrict__ Whh,
    float* __restrict__ hs, unsigned long long* hb)
{
    __shared__ float h_s[2][64 * HSPAD];  // h[k] at [par][(k>>4)*20 + (k&15)]
    const int tid  = threadIdx.x;
    const int wv   = tid >> 6;            // wave = unit slot 0..15
    const int lane = tid & 63;
    const int unit = blockIdx.x * 16 + wv;

    // weights: 4 gate rows (i,f,g,o) x 16 cols -> 16 float4 in VGPRs
    float4 w4[4][4];
#pragma unroll
    for (int q = 0; q < 4; ++q)
#pragma unroll
        for (int jj = 0; jj < 4; ++jj)
            w4[q][jj] = *(const float4*)(
                Whh + (size_t)(q * HDIM + unit) * KDIM + lane * 16 + jj * 4);

    for (int i = tid; i < 2 * 64 * HSPAD; i += SNT) ((float*)h_s)[i] = 0.0f;
    __syncthreads();

    float c = 0.0f;                       // redundant per-lane cell state
    const int sbase = lane * HSPAD;

    for (int t = 1; t <= NSTEP; ++t) {
        // Residency pin: weights loop-carried through an empty asm.
#pragma unroll
        for (int q = 0; q < 4; ++q) {
            PIN4(w4[q][0]); PIN4(w4[q][1]); PIN4(w4[q][2]); PIN4(w4[q][3]);
        }

        const int par = (t - 1) & 1;

        // xg loads overlap the spin below (lane q<4 fetches gate q)
        float xgv = 0.0f;
        if (lane < 4) xgv = xg[(size_t)(t - 1) * GDIM + lane * HDIM + unit];

        if (t > 1) {
            const int want = t - 1;
            const unsigned long long* p = hb + (size_t)par * HDIM + tid;
            unsigned long long v0;
            for (;;) {
                v0 = __hip_atomic_load(p, __ATOMIC_RELAXED, __HIP_MEMORY_SCOPE_AGENT);
                if ((int)(v0 >> 32) == want) break;
            }
            // seg-major padded store: h[k] -> (k>>4)*HSPAD + (k&15), k = tid
            h_s[par][(tid >> 4) * HSPAD + (tid & 15)] = __uint_as_float((unsigned)v0);
        }
        __syncthreads();   // (B) h_s[par] ready; also fences step t-1 reads
                           // (h_s[par] rewrite at t+2 comes after barrier t+1)

        // GEMV: 16 columns x 4 gate rows, h4 reused across rows, W in VGPRs
        float a0 = 0.0f, a1 = 0.0f, a2 = 0.0f, a3 = 0.0f;
#pragma unroll
        for (int jj = 0; jj < 4; ++jj) {
            const float4 h4 = *(const float4*)&h_s[par][sbase + jj * 4];
            a0 += w4[0][jj].x * h4.x + w4[0][jj].y * h4.y + w4[0][jj].z * h4.z + w4[0][jj].w * h4.w;
            a1 += w4[1][jj].x * h4.x + w4[1][jj].y * h4.y + w4[1][jj].z * h4.z + w4[1][jj].w * h4.w;
            a2 += w4[2][jj].x * h4.x + w4[2][jj].y * h4.y + w4[2][jj].z * h4.z + w4[2][jj].w * h4.w;
            a3 += w4[3][jj].x * h4.x + w4[3][jj].y * h4.y + w4[3][jj].z * h4.z + w4[3][jj].w * h4.w;
        }
        // fold xg into the right gate accumulator before the reduction
        a0 += (lane == 0) ? xgv : 0.0f;
        a1 += (lane == 1) ? xgv : 0.0f;
        a2 += (lane == 2) ? xgv : 0.0f;
        a3 += (lane == 3) ? xgv : 0.0f;
        // 6-stage butterfly over the full 64-lane wave
#pragma unroll
        for (int m = 1; m < 64; m <<= 1) {
            a0 += __shfl_xor(a0, m, 64);
            a1 += __shfl_xor(a1, m, 64);
            a2 += __shfl_xor(a2, m, 64);
            a3 += __shfl_xor(a3, m, 64);
        }

        const float ig = sigmoidf_(a0);
        const float fg = sigmoidf_(a1);
        const float gg = tanhf_(a2);
        const float og = sigmoidf_(a3);
        c = fg * c + ig * gg;
        const float h = og * tanhf_(c);

        if (lane == 0) {
            hs[(size_t)(t - 1) * HDIM + unit] = h;
            const unsigned long long pv =
                ((unsigned long long)(unsigned)t << 32) | __float_as_uint(h);
            __hip_atomic_store(&hb[(size_t)(t & 1) * HDIM + unit], pv,
                               __ATOMIC_RELAXED, __HIP_MEMORY_SCOPE_AGENT);
        }
        // no trailing barrier: parity + barrier(t+1) make h_s WAR-safe;
        // hb overwrite at t+2 is gated by the 2-step handoff slack.
    }
}

extern "C" void kernel_launch(void* const* d_in, const int* in_sizes, int n_in,
                              void* d_out, int out_size, void* d_ws, size_t ws_size,
                              hipStream_t stream)
{
    const int*   x     = (const int*)d_in[0];
    const float* emb   = (const float*)d_in[1];
    const float* W_ih  = (const float*)d_in[2];
    const float* W_hh  = (const float*)d_in[3];
    const float* b_ih  = (const float*)d_in[4];
    const float* b_hh  = (const float*)d_in[5];
    const float* W_out = (const float*)d_in[6];
    const float* b_out = (const float*)d_in[7];
    float* out = (float*)d_out;

    float* xg = (float*)d_ws;                          // 4095*4096 f32
    float* hs = xg + (size_t)NSTEP * GDIM;             // 4095*1024 f32
    unsigned long long* hb =
        (unsigned long long*)(hs + (size_t)NSTEP * HDIM);  // 2*1024 u64 (8B aligned)

    dim3 blk(256);
    dim3 g1(GDIM / 128, 32);                           // 32 x 32
    gemm_emb_kernel<<<g1, blk, 0, stream>>>(x, emb, W_ih, b_ih, b_hh, xg);

    scan_kernel<<<dim3(SNWG), dim3(SNT), 0, stream>>>(xg, W_hh, hs, hb);

    dim3 g2((CDIM + 127) / 128, 32);                   // 10 x 32
    gemm_out_kernel<<<g2, blk, 0, stream>>>(hs, W_out, b_out, out);
}

// Round 7
// 8366.760 us; speedup vs baseline: 1.8287x; 1.8287x over previous
//
#include <hip/hip_runtime.h>
#include <math.h>

#define NSTEP 4095   // T-1 sequence steps
#define EDIM  512
#define HDIM  1024
#define GDIM  4096   // 4*H
#define KDIM  1024   // 2E == H == 1024 for both GEMMs
#define CDIM  1221
#define SNWG  64     // scan workgroups
#define UNITS 16     // hidden units per scan WG

// In-loop residency pin (the single delta vs the proven round-0 kernel).
// v5->v6 proved this is worth -1.14us/step on the 8-wave config: the empty
// asm makes the weight values loop-carried, so the compiler cannot
// rematerialize the W_hh loads from L2 every step.
#define PIN4(v) asm volatile("" : "+v"((v).x), "+v"((v).y), "+v"((v).z), "+v"((v).w))

__device__ __forceinline__ float sigmoidf_(float v) {
    return 1.0f / (1.0f + __expf(-v));
}
__device__ __forceinline__ float tanhf_(float v) {
    v = fminf(fmaxf(v, -15.0f), 15.0f);      // avoid inf/inf NaN
    const float e2 = __expf(2.0f * v);
    return (e2 - 1.0f) / (e2 + 1.0f);
}

// ---------------------------------------------------------------------------
// GEMM1: xg[m][n] = sum_k A[m][k]*W_ih[n][k] + b_ih[n] + b_hh[n]
//   A[m][k] = emb[x[m]][k] (k<512) ; emb[x[4095]][k-512] (k>=512)
// ---------------------------------------------------------------------------
__global__ __launch_bounds__(256) void gemm_emb_kernel(
    const int* __restrict__ x, const float* __restrict__ emb,
    const float* __restrict__ W, const float* __restrict__ b_ih,
    const float* __restrict__ b_hh, float* __restrict__ xg)
{
    __shared__ float As[8][128];
    __shared__ float Bs[8][128];
    const int tid = threadIdx.x;
    const int bm = blockIdx.y * 128, bn = blockIdx.x * 128;
    const int tx = tid & 15, ty = tid >> 4;
    const int lrow = tid >> 1;
    const int lk4  = (tid & 1) * 4;
    const int lastTok = x[NSTEP];
    const int am = bm + lrow;
    const int tokRow = (am < NSTEP) ? x[am] : 0;
    const int bnrow = bn + lrow;

    float acc[8][8];
#pragma unroll
    for (int i = 0; i < 8; ++i)
#pragma unroll
        for (int j = 0; j < 8; ++j) acc[i][j] = 0.0f;

    for (int k0 = 0; k0 < KDIM; k0 += 8) {
        const int k = k0 + lk4;
        float4 av = make_float4(0.f, 0.f, 0.f, 0.f);
        if (am < NSTEP) {
            const int tok = (k < EDIM) ? tokRow : lastTok;
            const int kk  = (k < EDIM) ? k : (k - EDIM);
            av = *(const float4*)(emb + (size_t)tok * EDIM + kk);
        }
        const float4 bv = *(const float4*)(W + (size_t)bnrow * KDIM + k);
        __syncthreads();
        As[lk4 + 0][lrow] = av.x; As[lk4 + 1][lrow] = av.y;
        As[lk4 + 2][lrow] = av.z; As[lk4 + 3][lrow] = av.w;
        Bs[lk4 + 0][lrow] = bv.x; Bs[lk4 + 1][lrow] = bv.y;
        Bs[lk4 + 2][lrow] = bv.z; Bs[lk4 + 3][lrow] = bv.w;
        __syncthreads();
#pragma unroll
        for (int kk = 0; kk < 8; ++kk) {
            const float4 a0 = *(const float4*)&As[kk][ty * 4];
            const float4 a1 = *(const float4*)&As[kk][ty * 4 + 64];
            const float4 b0 = *(const float4*)&Bs[kk][tx * 4];
            const float4 b1 = *(const float4*)&Bs[kk][tx * 4 + 64];
            const float a[8] = {a0.x, a0.y, a0.z, a0.w, a1.x, a1.y, a1.z, a1.w};
            const float b[8] = {b0.x, b0.y, b0.z, b0.w, b1.x, b1.y, b1.z, b1.w};
#pragma unroll
            for (int i = 0; i < 8; ++i)
#pragma unroll
                for (int j = 0; j < 8; ++j) acc[i][j] += a[i] * b[j];
        }
    }
#pragma unroll
    for (int i = 0; i < 8; ++i) {
        const int m = bm + ((i < 4) ? (ty * 4 + i) : (64 + ty * 4 + i - 4));
        if (m >= NSTEP) continue;
#pragma unroll
        for (int j = 0; j < 8; ++j) {
            const int n = bn + ((j < 4) ? (tx * 4 + j) : (64 + tx * 4 + j - 4));
            xg[(size_t)m * GDIM + n] = acc[i][j] + b_ih[n] + b_hh[n];
        }
    }
}

// ---------------------------------------------------------------------------
// GEMM2: out[m][n] = sum_k hs[m][k]*W_out[n][k] + b_out[n]   (N=1221)
// ---------------------------------------------------------------------------
__global__ __launch_bounds__(256) void gemm_out_kernel(
    const float* __restrict__ A, const float* __restrict__ W,
    const float* __restrict__ bias, float* __restrict__ C)
{
    __shared__ float As[8][128];
    __shared__ float Bs[8][128];
    const int tid = threadIdx.x;
    const int bm = blockIdx.y * 128, bn = blockIdx.x * 128;
    const int tx = tid & 15, ty = tid >> 4;
    const int lrow = tid >> 1;
    const int lk4  = (tid & 1) * 4;
    const int am = bm + lrow;
    const int bnrow = bn + lrow;

    float acc[8][8];
#pragma unroll
    for (int i = 0; i < 8; ++i)
#pragma unroll
        for (int j = 0; j < 8; ++j) acc[i][j] = 0.0f;

    for (int k0 = 0; k0 < KDIM; k0 += 8) {
        const int k = k0 + lk4;
        float4 av = make_float4(0.f, 0.f, 0.f, 0.f);
        if (am < NSTEP) av = *(const float4*)(A + (size_t)am * KDIM + k);
        float4 bv = make_float4(0.f, 0.f, 0.f, 0.f);
        if (bnrow < CDIM) bv = *(const float4*)(W + (size_t)bnrow * KDIM + k);
        __syncthreads();
        As[lk4 + 0][lrow] = av.x; As[lk4 + 1][lrow] = av.y;
        As[lk4 + 2][lrow] = av.z; As[lk4 + 3][lrow] = av.w;
        Bs[lk4 + 0][lrow] = bv.x; Bs[lk4 + 1][lrow] = bv.y;
        Bs[lk4 + 2][lrow] = bv.z; Bs[lk4 + 3][lrow] = bv.w;
        __syncthreads();
#pragma unroll
        for (int kk = 0; kk < 8; ++kk) {
            const float4 a0 = *(const float4*)&As[kk][ty * 4];
            const float4 a1 = *(const float4*)&As[kk][ty * 4 + 64];
            const float4 b0 = *(const float4*)&Bs[kk][tx * 4];
            const float4 b1 = *(const float4*)&Bs[kk][tx * 4 + 64];
            const float a[8] = {a0.x, a0.y, a0.z, a0.w, a1.x, a1.y, a1.z, a1.w};
            const float b[8] = {b0.x, b0.y, b0.z, b0.w, b1.x, b1.y, b1.z, b1.w};
#pragma unroll
            for (int i = 0; i < 8; ++i)
#pragma unroll
                for (int j = 0; j < 8; ++j) acc[i][j] += a[i] * b[j];
        }
    }
#pragma unroll
    for (int i = 0; i < 8; ++i) {
        const int m = bm + ((i < 4) ? (ty * 4 + i) : (64 + ty * 4 + i - 4));
        if (m >= NSTEP) continue;
#pragma unroll
        for (int j = 0; j < 8; ++j) {
            const int n = bn + ((j < 4) ? (tx * 4 + j) : (64 + tx * 4 + j - 4));
            if (n < CDIM) C[(size_t)m * CDIM + n] = acc[i][j] + bias[n];
        }
    }
}

// ---------------------------------------------------------------------------
// Persistent LSTM scan, v8 = EXACT round-0 v3 (the proven best: 1.80us/step)
// + in-loop PIN4 (the single delta). 64 WGs x 1024 threads; WG g owns hidden
// units g*16..g*16+15 (64 gate rows; weights in 64 VGPRs/thread).
// Handoff: tagged 64-bit payloads hb[parity][i] = (step<<32)|bits(h_i).
// The poll IS the data load (tag+value atomic in one 8B word -> no fences,
// no flag indirection). Parity double-buffer; 2-step production slack
// guarantees no overrun.
// v4-v7 post-mortems: all scan restructures regressed (extra 34-97MB
// WRITE_SIZE vs v3's clean 50MB = structural hb+hs exactly); v3 is the
// empirical optimum. Only remaining proven lever: in-loop pin (v5->v6:
// -1.14us/step). If this spills (WRITE_SIZE > ~55MB), pin is rejected at
// the 16-wave/128-VGPR budget.
// ---------------------------------------------------------------------------
__global__ __launch_bounds__(1024, 4) void scan_kernel(
    const float* __restrict__ xg, const float* __restrict__ Whh,
    float* __restrict__ hs, unsigned long long* hb)
{
    __shared__ float h_s[HDIM];
    __shared__ float gate_s[64];
    __shared__ float c_s[UNITS];
    const int g = blockIdx.x, tid = threadIdx.x;
    const int lane = tid & 63, wv = tid >> 6;    // 16 waves
    const int seg = tid & 15, lr = tid >> 4;     // lr = row 0..63
    const int q = lr >> 4, j = lr & 15;          // gate q, unit j
    const int grow = q * HDIM + g * UNITS + j;   // gate row in W_hh

    // weights: thread covers cols i*64 + seg*4 .. +3, i = 0..15
    float4 w4[16];
#pragma unroll
    for (int i = 0; i < 16; ++i)
        w4[i] = *(const float4*)(Whh + (size_t)grow * KDIM + i * 64 + seg * 4);

    for (int i = tid; i < HDIM; i += 1024) h_s[i] = 0.0f;
    if (tid < UNITS) c_s[tid] = 0.0f;
    __syncthreads();

    for (int t = 1; t <= NSTEP; ++t) {
        // THE single delta vs round-0: loop-carried residency pin.
#pragma unroll
        for (int i = 0; i < 16; ++i) PIN4(w4[i]);

        // xg load overlaps the spin below (independent)
        float xgv = 0.0f;
        if (seg == 0) xgv = xg[(size_t)(t - 1) * GDIM + grow];

        if (t > 1) {
            const int par = (t - 1) & 1;
            const int el = wv * 64 + lane;       // each wave owns 64 h values
            const int want = t - 1;
            unsigned long long v;
            for (;;) {
                v = __hip_atomic_load(&hb[par * HDIM + el], __ATOMIC_RELAXED,
                                      __HIP_MEMORY_SCOPE_AGENT);
                if ((int)(v >> 32) == want) break;   // per-lane spin
            }
            h_s[el] = __uint_as_float((unsigned)v);
        }
        __syncthreads();   // (B) h_s ready

        // GEMV: this thread's 64 columns of its gate row
        float acc = 0.0f;
#pragma unroll
        for (int i = 0; i < 16; ++i) {
            const float4 h4 = *(const float4*)&h_s[i * 64 + seg * 4];
            acc += w4[i].x * h4.x + w4[i].y * h4.y +
                   w4[i].z * h4.z + w4[i].w * h4.w;
        }
        acc += __shfl_xor(acc, 1, 64);
        acc += __shfl_xor(acc, 2, 64);
        acc += __shfl_xor(acc, 4, 64);
        acc += __shfl_xor(acc, 8, 64);
        if (seg == 0) gate_s[lr] = acc + xgv;
        __syncthreads();   // (C) gate_s ready; all h_s reads complete

        if (tid < UNITS) {
            const int jj = tid;
            const float ig = sigmoidf_(gate_s[jj]);
            const float fg = sigmoidf_(gate_s[16 + jj]);
            const float gg = tanhf_(gate_s[32 + jj]);
            const float og = sigmoidf_(gate_s[48 + jj]);
            const float c  = fg * c_s[jj] + ig * gg;
            c_s[jj] = c;
            const float h = og * tanhf_(c);
            hs[(size_t)(t - 1) * HDIM + g * UNITS + jj] = h;
            const unsigned long long pv =
                ((unsigned long long)(unsigned)t << 32) | __float_as_uint(h);
            __hip_atomic_store(&hb[(t & 1) * HDIM + g * UNITS + jj], pv,
                               __ATOMIC_RELAXED, __HIP_MEMORY_SCOPE_AGENT);
        }
        // no trailing barrier: next-iter writes to h_s/gate_s are gated by
        // the spin (needs OUR tag-t store) resp. barrier (B) of t+1.
    }
}

extern "C" void kernel_launch(void* const* d_in, const int* in_sizes, int n_in,
                              void* d_out, int out_size, void* d_ws, size_t ws_size,
                              hipStream_t stream)
{
    const int*   x     = (const int*)d_in[0];
    const float* emb   = (const float*)d_in[1];
    const float* W_ih  = (const float*)d_in[2];
    const float* W_hh  = (const float*)d_in[3];
    const float* b_ih  = (const float*)d_in[4];
    const float* b_hh  = (const float*)d_in[5];
    const float* W_out = (const float*)d_in[6];
    const float* b_out = (const float*)d_in[7];
    float* out = (float*)d_out;

    float* xg = (float*)d_ws;                          // 4095*4096 f32
    float* hs = xg + (size_t)NSTEP * GDIM;             // 4095*1024 f32
    unsigned long long* hb =
        (unsigned long long*)(hs + (size_t)NSTEP * HDIM);  // 2*1024 u64 (8B aligned)

    dim3 blk(256);
    dim3 g1(GDIM / 128, 32);                           // 32 x 32
    gemm_emb_kernel<<<g1, blk, 0, stream>>>(x, emb, W_ih, b_ih, b_hh, xg);

    scan_kernel<<<dim3(SNWG), dim3(1024), 0, stream>>>(xg, W_hh, hs, hb);

    dim3 g2((CDIM + 127) / 128, 32);                   // 10 x 32
    gemm_out_kernel<<<g2, blk, 0, stream>>>(hs, W_out, b_out, out);
}